// Round 3
// baseline (245.949 us; speedup 1.0000x reference)
//
#include <hip/hip_runtime.h>

#define ROW_LEN 2048
#define BLOCK   256
#define EPS     1e-5f

typedef float floatx4 __attribute__((ext_vector_type(4)));

// Row scales live in device-global BSS: no hipMalloc, graph-capture safe.
// 32768 rows max (problem has 16384).
__device__ float g_row_scale[32768];

// ---------------- Pass 1: pure read stream + per-row reduce ----------------
// One 64-lane wave per row: 64 lanes x 8 float4 = 2048 floats.
__global__ __launch_bounds__(BLOCK) void RMSNorm_pass1_kernel(
    const float* __restrict__ x, int rows)
{
    const int wave = threadIdx.x >> 6;
    const int lane = threadIdx.x & 63;
    const int row  = blockIdx.x * (BLOCK / 64) + wave;
    if (row >= rows) return;

    const float4* __restrict__ xr =
        reinterpret_cast<const float4*>(x + (size_t)row * ROW_LEN) + lane;

    float4 v[8];
    #pragma unroll
    for (int j = 0; j < 8; ++j) v[j] = xr[j * 64];

    float s0 = 0.f, s1 = 0.f, s2 = 0.f, s3 = 0.f;
    #pragma unroll
    for (int j = 0; j < 8; ++j) {
        s0 += v[j].x * v[j].x;
        s1 += v[j].y * v[j].y;
        s2 += v[j].z * v[j].z;
        s3 += v[j].w * v[j].w;
    }
    float ss = (s0 + s1) + (s2 + s3);

    #pragma unroll
    for (int off = 32; off > 0; off >>= 1)
        ss += __shfl_xor(ss, off, 64);

    if (lane == 0)
        g_row_scale[row] = rsqrtf(ss * (1.0f / (float)ROW_LEN) + EPS);
}

// ---------------- Pass 2: fill-like scale stream ----------------
// Pure grid-stride: out[i] = x[i] * scale[row] * g[col]. No reduce, no
// shuffles, no barriers — same shape as the 6.6 TB/s fill. x re-read is
// LLC-hot from pass 1; nt stores keep out from evicting x mid-pass.
__global__ __launch_bounds__(BLOCK) void RMSNorm_pass2_kernel(
    const float* __restrict__ x, const float* __restrict__ g,
    float* __restrict__ out, int n4)
{
    const floatx4* __restrict__ x4 = reinterpret_cast<const floatx4*>(x);
    const floatx4* __restrict__ g4 = reinterpret_cast<const floatx4*>(g);
    floatx4* __restrict__       o4 = reinterpret_cast<floatx4*>(out);

    const int stride = gridDim.x * BLOCK;
    for (int i = blockIdx.x * BLOCK + threadIdx.x; i < n4; i += stride) {
        const floatx4 xv = x4[i];
        const int row = i >> 9;        // 512 float4 per row
        const int col = i & 511;
        const float s = g_row_scale[row];
        const floatx4 gv = g4[col];
        floatx4 ov = xv * s * gv;
        __builtin_nontemporal_store(ov, &o4[i]);
    }
}

extern "C" void kernel_launch(void* const* d_in, const int* in_sizes, int n_in,
                              void* d_out, int out_size, void* d_ws, size_t ws_size,
                              hipStream_t stream) {
    const float* x = (const float*)d_in[0];
    const float* g = (const float*)d_in[1];
    float* out = (float*)d_out;

    const int rows = in_sizes[0] / ROW_LEN;   // 16384
    const int n4   = rows * (ROW_LEN / 4);    // 8388608 float4

    const int grid1 = (rows + (BLOCK / 64) - 1) / (BLOCK / 64);  // 4096
    RMSNorm_pass1_kernel<<<grid1, BLOCK, 0, stream>>>(x, rows);

    // 4096 blocks, 16/CU; each thread handles 8 float4, grid-stride coalesced.
    const int grid2 = 4096;
    RMSNorm_pass2_kernel<<<grid2, BLOCK, 0, stream>>>(x, g, out, n4);
}